// Round 14
// baseline (295.984 us; speedup 1.0000x reference)
//
#include <hip/hip_runtime.h>
#include <hip/hip_bf16.h>
#include <hip/hip_cooperative_groups.h>

namespace cg = cooperative_groups;

#define NN 8192
#define DD 128
#define BB 4096

#define ROWS_PER_BLOCK 128           // 4 waves * 32 rows (2 rowfrags)
#define COLSPLIT 16
#define COLS_PER_BLOCK (NN / COLSPLIT)   // 512
#define TILES (COLS_PER_BLOCK / 64)      // 8 tiles of 64 cols
#define GRID_X (NN / ROWS_PER_BLOCK)     // 64
#define NBLOCKS (GRID_X * COLSPLIT)      // 1024 = 4 blocks/CU exactly

// alpha^2 = 2*log2(e); scaling zn by alpha makes the MFMA dot product equal
// the exp2 argument directly: exp2(acc) = exp(sim).
#define ALPHA 1.69864354f
#define LN2 0.6931471805599453f

typedef __attribute__((ext_vector_type(8))) short short8;
typedef __attribute__((ext_vector_type(4))) float f32x4;

typedef __attribute__((address_space(3))) unsigned lds_u32;
typedef __attribute__((address_space(1))) unsigned glb_u32;

static __device__ __forceinline__ float fast_exp2(float x) {
#if __has_builtin(__builtin_amdgcn_exp2f)
  return __builtin_amdgcn_exp2f(x);   // bare v_exp_f32
#else
  float r;
  asm("v_exp_f32 %0, %1" : "=v"(r) : "v"(x));
  return r;
#endif
}

// ---- phase 0: normalize -> alpha-scaled bf16, pos dot, self dot, zero -----
// Each block preps 4 row-pairs (r, r+BB); wave w owns pair r = 4*bid + w,
// holding both rows in registers (2 elems/lane each) -> no LDS exchange.
static __device__ __forceinline__ void prep_work(
    const float* __restrict__ zi, const float* __restrict__ zj,
    __hip_bfloat16* __restrict__ zn, float* __restrict__ posh,
    float* __restrict__ sd, float* __restrict__ rowsum,
    int* __restrict__ rowcnt, int bid) {
  const int w = threadIdx.x >> 6;
  const int lane = threadIdx.x & 63;
  const int r = 4 * bid + w;                  // 0..4095
  const float2 va =
      *reinterpret_cast<const float2*>(zi + (size_t)r * DD + lane * 2);
  const float2 vb =
      *reinterpret_cast<const float2*>(zj + (size_t)r * DD + lane * 2);
  float ssa = va.x * va.x + va.y * va.y;
  float ssb = vb.x * vb.x + vb.y * vb.y;
  #pragma unroll
  for (int m = 1; m < 64; m <<= 1) {
    ssa += __shfl_xor(ssa, m, 64);
    ssb += __shfl_xor(ssb, m, 64);
  }
  const float ia = ALPHA / fmaxf(sqrtf(ssa), 1e-8f);
  const float ib = ALPHA / fmaxf(sqrtf(ssb), 1e-8f);
  __hip_bfloat16 a0 = __float2bfloat16(va.x * ia);
  __hip_bfloat16 a1 = __float2bfloat16(va.y * ia);
  __hip_bfloat16 b0 = __float2bfloat16(vb.x * ib);
  __hip_bfloat16 b1 = __float2bfloat16(vb.y * ib);
  *reinterpret_cast<__hip_bfloat162*>(zn + (size_t)r * DD + lane * 2) =
      __hip_bfloat162{a0, a1};
  *reinterpret_cast<__hip_bfloat162*>(zn + (size_t)(r + BB) * DD + lane * 2) =
      __hip_bfloat162{b0, b1};
  // bf16-rounded scaled values (what the MFMA phase consumes)
  float fa0 = __bfloat162float(a0), fa1 = __bfloat162float(a1);
  float fb0 = __bfloat162float(b0), fb1 = __bfloat162float(b1);
  float sqa = fa0 * fa0 + fa1 * fa1;
  float sqb = fb0 * fb0 + fb1 * fb1;
  float dp = fa0 * fb0 + fa1 * fb1;
  #pragma unroll
  for (int m = 1; m < 64; m <<= 1) {
    sqa += __shfl_xor(sqa, m, 64);
    sqb += __shfl_xor(sqb, m, 64);
    dp += __shfl_xor(dp, m, 64);
  }
  if (lane == 0) {
    sd[r] = sqa;              // = exp2-arg of sim_ii
    sd[r + BB] = sqb;
    posh[r] = dp;             // pos_i = ln2 * posh  (symmetric pair)
    posh[r + BB] = dp;
    rowsum[r] = 0.0f;
    rowsum[r + BB] = 0.0f;
    rowcnt[r] = 0;
    rowcnt[r + BB] = 0;
  }
}

// ---- phase 1: fused sim GEMM + exp-rowsum + count -------------------------
static __device__ __forceinline__ void main_work(
    const __hip_bfloat16* __restrict__ zn, const float* __restrict__ posh,
    float* __restrict__ rowsum, int* __restrict__ rowcnt, int bx, int by) {
  __shared__ char ldsbuf[2][16384];   // double-buffered 64-col x 128-k bf16 tile

  const int tid = threadIdx.x;
  const int w = tid >> 6;
  const int lane = tid & 63;
  const int lo = lane & 15, hi = lane >> 4;
  const int rowBase = bx * ROWS_PER_BLOCK;
  const int colBase = by * COLS_PER_BLOCK;
  const short* znS = reinterpret_cast<const short*>(zn);

  // Staging: tile buffer layout [col][chunk] with 16B chunk XOR-swizzled by
  // (col&7). global_load_lds writes linearly (base + lane*16), so the swizzle
  // is applied on the SOURCE address (rule 21).
  #define STAGE(bufidx, gcol0)                                               \
    {                                                                        \
      _Pragma("unroll")                                                      \
      for (int q = 0; q < 4; ++q) {                                          \
        int s_ = 4 * w + q;                                                  \
        int coll_ = 4 * s_ + (lane >> 4);                                    \
        int lc_ = (lane & 15) ^ (coll_ & 7);                                 \
        const short* src_ = znS + (size_t)((gcol0) + coll_) * DD + lc_ * 8;  \
        __builtin_amdgcn_global_load_lds(                                    \
            (const glb_u32*)src_, (lds_u32*)(&ldsbuf[bufidx][s_ * 1024]),    \
            16, 0, 0);                                                       \
      }                                                                      \
    }

  STAGE(0, colBase);

  // A fragments: 2 row-frags x 4 k-chunks, registers for whole phase.
  short8 a[2][4];
  #pragma unroll
  for (int rf = 0; rf < 2; ++rf) {
    int arow = rowBase + 32 * w + 16 * rf + lo;
    const short* p = znS + (size_t)arow * DD + 8 * hi;
    #pragma unroll
    for (int c = 0; c < 4; ++c)
      a[rf][c] = *reinterpret_cast<const short8*>(p + 32 * c);
  }

  float posv[2][4];
  float sume[2][4];
  int cntv[2][4];
  #pragma unroll
  for (int rf = 0; rf < 2; ++rf)
    #pragma unroll
    for (int r = 0; r < 4; ++r) {
      // C/D layout: col = lane&15, row = 4*(lane>>4)+reg  [m89/m91]
      posv[rf][r] = posh[rowBase + 32 * w + 16 * rf + 4 * hi + r];
      sume[rf][r] = 0.0f;
      cntv[rf][r] = 0;
    }

  __syncthreads();   // tile 0 staged (vmcnt(0) drain)

  #pragma unroll 2
  for (int t = 0; t < TILES; ++t) {
    if (t + 1 < TILES) STAGE((t + 1) & 1, colBase + (t + 1) * 64);
    #pragma unroll
    for (int cf = 0; cf < 4; ++cf) {
      short8 b[4];
      #pragma unroll
      for (int c = 0; c < 4; ++c) {
        int coll = 16 * cf + lo;
        int off = coll * 256 + 16 * ((hi + 4 * c) ^ (lo & 7));
        b[c] = *reinterpret_cast<const short8*>(&ldsbuf[t & 1][off]);
      }
      #pragma unroll
      for (int rf = 0; rf < 2; ++rf) {
        f32x4 acc = {0.0f, 0.0f, 0.0f, 0.0f};
        #pragma unroll
        for (int c = 0; c < 4; ++c)
          acc = __builtin_amdgcn_mfma_f32_16x16x32_bf16(a[rf][c], b[c], acc,
                                                        0, 0, 0);
        #pragma unroll
        for (int r = 0; r < 4; ++r) {
          float s = acc[r];                 // = alpha^2 * dot = exp2 arg
          sume[rf][r] += fast_exp2(s);      // exp(sim), single v_exp_f32
          cntv[rf][r] += (posv[rf][r] > s) ? 1 : 0;
        }
      }
    }
    __syncthreads();
  }

  // reduce across the 16 lanes (bits 0..3) that share a row, then atomics
  #pragma unroll
  for (int rf = 0; rf < 2; ++rf)
    #pragma unroll
    for (int r = 0; r < 4; ++r) {
      float v = sume[rf][r];
      int c2 = cntv[rf][r];
      #pragma unroll
      for (int m = 1; m < 16; m <<= 1) {
        v += __shfl_xor(v, m, 64);
        c2 += __shfl_xor(c2, m, 64);
      }
      if (lo == 0) {
        int row = rowBase + 32 * w + 16 * rf + 4 * hi + r;
        atomicAdd(&rowsum[row], v);
        atomicAdd(&rowcnt[row], c2);
      }
    }
  #undef STAGE
}

// ---- phase 2: finalize (one 256-thread block) ------------------------------
static __device__ __forceinline__ void finalize_work(
    const float* __restrict__ rowsum, const int* __restrict__ rowcnt,
    const float* __restrict__ posh, const float* __restrict__ sd,
    float* __restrict__ out) {
  int tid = threadIdx.x;
  float lsum = 0.0f;
  unsigned csum = 0;
  #pragma unroll
  for (int k = 0; k < NN / 256; ++k) {
    int i = tid + k * 256;
    float diag = fast_exp2(sd[i]);            // exp(sim_ii)
    lsum += logf(rowsum[i] - diag) - LN2 * posh[i];  // lse_i - pos_i
    csum += (unsigned)rowcnt[i];
  }
  #pragma unroll
  for (int m = 1; m < 64; m <<= 1) {
    lsum += __shfl_xor(lsum, m, 64);
    csum += __shfl_xor(csum, m, 64);
  }
  __shared__ float ls[4];
  __shared__ unsigned cs[4];
  int w = tid >> 6, lane = tid & 63;
  if (lane == 0) { ls[w] = lsum; cs[w] = csum; }
  __syncthreads();
  if (tid == 0) {
    float L = ls[0] + ls[1] + ls[2] + ls[3];
    unsigned long long C =
        (unsigned long long)cs[0] + cs[1] + cs[2] + cs[3];
    out[0] = L / (float)NN;
    out[1] = (float)((double)C / ((double)NN * (double)NN));
  }
}

// ---- cooperative mono-kernel: prep -> sync -> GEMM -> sync -> finalize ----
__global__ __launch_bounds__(256, 4) void mono_kernel(
    const float* __restrict__ zi, const float* __restrict__ zj,
    __hip_bfloat16* __restrict__ zn, float* __restrict__ posh,
    float* __restrict__ sd, float* __restrict__ rowsum,
    int* __restrict__ rowcnt, float* __restrict__ out) {
  const int bid = blockIdx.x + blockIdx.y * gridDim.x;
  prep_work(zi, zj, zn, posh, sd, rowsum, rowcnt, bid);
  cg::this_grid().sync();
  main_work(zn, posh, rowsum, rowcnt, blockIdx.x, blockIdx.y);
  cg::this_grid().sync();
  if (bid == 0) finalize_work(rowsum, rowcnt, posh, sd, out);
}

// ---- fallback path: same phases as 3 plain kernels ------------------------
__global__ __launch_bounds__(256) void prep_kernel(
    const float* __restrict__ zi, const float* __restrict__ zj,
    __hip_bfloat16* __restrict__ zn, float* __restrict__ posh,
    float* __restrict__ sd, float* __restrict__ rowsum,
    int* __restrict__ rowcnt) {
  prep_work(zi, zj, zn, posh, sd, rowsum, rowcnt, blockIdx.x);
}

__global__ __launch_bounds__(256) void main_kernel(
    const __hip_bfloat16* __restrict__ zn, const float* __restrict__ posh,
    float* __restrict__ rowsum, int* __restrict__ rowcnt) {
  main_work(zn, posh, rowsum, rowcnt, blockIdx.x, blockIdx.y);
}

__global__ __launch_bounds__(256) void finalize_kernel(
    const float* __restrict__ rowsum, const int* __restrict__ rowcnt,
    const float* __restrict__ posh, const float* __restrict__ sd,
    float* __restrict__ out) {
  finalize_work(rowsum, rowcnt, posh, sd, out);
}

extern "C" void kernel_launch(void* const* d_in, const int* in_sizes, int n_in,
                              void* d_out, int out_size, void* d_ws,
                              size_t ws_size, hipStream_t stream) {
  const float* zi = (const float*)d_in[0];
  const float* zj = (const float*)d_in[1];
  float* out = (float*)d_out;

  __hip_bfloat16* zn = (__hip_bfloat16*)d_ws;                  // 2 MB
  float* posh = (float*)((char*)d_ws + (size_t)NN * DD * 2);   // 32 KB each
  float* sd = posh + NN;
  float* rowsum = sd + NN;
  int* rowcnt = (int*)(rowsum + NN);

  void* args[] = {(void*)&zi, (void*)&zj, (void*)&zn, (void*)&posh,
                  (void*)&sd, (void*)&rowsum, (void*)&rowcnt, (void*)&out};
  hipError_t err = hipLaunchCooperativeKernel(
      (const void*)mono_kernel, dim3(GRID_X, COLSPLIT), dim3(256), args, 0,
      stream);
  if (err != hipSuccess) {
    // deterministic fallback: identical phases as separate launches
    prep_kernel<<<NBLOCKS, 256, 0, stream>>>(zi, zj, zn, posh, sd, rowsum,
                                             rowcnt);
    main_kernel<<<dim3(GRID_X, COLSPLIT), 256, 0, stream>>>(zn, posh, rowsum,
                                                            rowcnt);
    finalize_kernel<<<1, 256, 0, stream>>>(rowsum, rowcnt, posh, sd, out);
  }
}